// Round 1
// baseline (24572.423 us; speedup 1.0000x reference)
//
#include <hip/hip_runtime.h>
#include <math.h>

#define B_  4
#define S_  1024
#define D_  2048
#define NL_ 2
#define H_  16
#define KV_ 4
#define F_  8192
#define R_  16
#define HD_ 128
#define BS_ (B_*S_)   // 4096 tokens

// ------------------------------------------------------------------
// embedding gather: x[tok,:] = embed[ids[tok],:]
__global__ void embed_kernel(const float* __restrict__ embed,
                             const int* __restrict__ ids,
                             float* __restrict__ x) {
    int tok = blockIdx.x;
    int id  = ids[tok];
    const float4* src = (const float4*)(embed + (size_t)id * D_);
    float4*       dst = (float4*)(x + (size_t)tok * D_);
    for (int i = threadIdx.x; i < D_/4; i += blockDim.x) dst[i] = src[i];
}

// ------------------------------------------------------------------
// rmsnorm per row of 2048
__global__ __launch_bounds__(256) void rmsnorm_kernel(const float* __restrict__ x,
                                                      const float* __restrict__ w,
                                                      float* __restrict__ out) {
    int row = blockIdx.x;
    const float4* xr = (const float4*)(x + (size_t)row * D_);
    float ss = 0.f;
    for (int i = threadIdx.x; i < D_/4; i += 256) {
        float4 v = xr[i];
        ss += v.x*v.x + v.y*v.y + v.z*v.z + v.w*v.w;
    }
    __shared__ float red[4];
    for (int off = 32; off; off >>= 1) ss += __shfl_down(ss, off);
    if ((threadIdx.x & 63) == 0) red[threadIdx.x >> 6] = ss;
    __syncthreads();
    float tot = red[0] + red[1] + red[2] + red[3];
    float scale = rsqrtf(tot / (float)D_ + 1e-5f);
    const float4* w4 = (const float4*)w;
    float4* o4 = (float4*)(out + (size_t)row * D_);
    for (int i = threadIdx.x; i < D_/4; i += 256) {
        float4 v = xr[i], g = w4[i], r;
        r.x = v.x*scale*g.x; r.y = v.y*scale*g.y;
        r.z = v.z*scale*g.z; r.w = v.w*scale*g.w;
        o4[i] = r;
    }
}

// ------------------------------------------------------------------
// generic f32 GEMM: C[M,N] (+)= A[M,K] @ B[K,N], 64x64 tile, 4x4/thread
#define TM 64
#define TN 64
#define TK 16

template<int ACC>
__global__ __launch_bounds__(256) void gemm_f32(const float* __restrict__ A,
                                                const float* __restrict__ Bm,
                                                float* __restrict__ C,
                                                int M, int N, int K) {
    __shared__ float As[TK][TM + 1];
    __shared__ float Bs[TK][TN + 1];
    int n0 = blockIdx.x * TN, m0 = blockIdx.y * TM;
    int t = threadIdx.x;
    int tm = (t >> 4) << 2, tn = (t & 15) << 2;
    float acc[4][4] = {};
    for (int k0 = 0; k0 < K; k0 += TK) {
        #pragma unroll
        for (int i = 0; i < 4; i++) {
            int idx = t + i * 256;
            int m = idx >> 4, kk = idx & 15;
            As[kk][m] = A[(size_t)(m0 + m) * K + k0 + kk];
        }
        #pragma unroll
        for (int i = 0; i < 4; i++) {
            int idx = t + i * 256;
            int kk = idx >> 6, n = idx & 63;
            Bs[kk][n] = Bm[(size_t)(k0 + kk) * N + n0 + n];
        }
        __syncthreads();
        #pragma unroll
        for (int kk = 0; kk < TK; kk++) {
            float a0 = As[kk][tm], a1 = As[kk][tm+1], a2 = As[kk][tm+2], a3 = As[kk][tm+3];
            float b0 = Bs[kk][tn], b1 = Bs[kk][tn+1], b2 = Bs[kk][tn+2], b3 = Bs[kk][tn+3];
            acc[0][0] += a0*b0; acc[0][1] += a0*b1; acc[0][2] += a0*b2; acc[0][3] += a0*b3;
            acc[1][0] += a1*b0; acc[1][1] += a1*b1; acc[1][2] += a1*b2; acc[1][3] += a1*b3;
            acc[2][0] += a2*b0; acc[2][1] += a2*b1; acc[2][2] += a2*b2; acc[2][3] += a2*b3;
            acc[3][0] += a3*b0; acc[3][1] += a3*b1; acc[3][2] += a3*b2; acc[3][3] += a3*b3;
        }
        __syncthreads();
    }
    #pragma unroll
    for (int i = 0; i < 4; i++)
        #pragma unroll
        for (int j = 0; j < 4; j++) {
            size_t off = (size_t)(m0 + tm + i) * N + n0 + tn + j;
            C[off] = (ACC ? C[off] : 0.f) + acc[i][j];
        }
}

// fused gate/up GEMM with SiLU*up epilogue: act = silu(A@Bg) * (A@Bu)
__global__ __launch_bounds__(256) void gemm_gateup(const float* __restrict__ A,
                                                   const float* __restrict__ Bg,
                                                   const float* __restrict__ Bu,
                                                   float* __restrict__ Cact,
                                                   int M, int N, int K) {
    __shared__ float As[TK][TM + 1];
    __shared__ float Bgs[TK][TN + 1];
    __shared__ float Bus[TK][TN + 1];
    int n0 = blockIdx.x * TN, m0 = blockIdx.y * TM;
    int t = threadIdx.x;
    int tm = (t >> 4) << 2, tn = (t & 15) << 2;
    float accg[4][4] = {};
    float accu[4][4] = {};
    for (int k0 = 0; k0 < K; k0 += TK) {
        #pragma unroll
        for (int i = 0; i < 4; i++) {
            int idx = t + i * 256;
            int m = idx >> 4, kk = idx & 15;
            As[kk][m] = A[(size_t)(m0 + m) * K + k0 + kk];
        }
        #pragma unroll
        for (int i = 0; i < 4; i++) {
            int idx = t + i * 256;
            int kk = idx >> 6, n = idx & 63;
            Bgs[kk][n] = Bg[(size_t)(k0 + kk) * N + n0 + n];
            Bus[kk][n] = Bu[(size_t)(k0 + kk) * N + n0 + n];
        }
        __syncthreads();
        #pragma unroll
        for (int kk = 0; kk < TK; kk++) {
            float a0 = As[kk][tm], a1 = As[kk][tm+1], a2 = As[kk][tm+2], a3 = As[kk][tm+3];
            float g0 = Bgs[kk][tn], g1 = Bgs[kk][tn+1], g2 = Bgs[kk][tn+2], g3 = Bgs[kk][tn+3];
            float u0 = Bus[kk][tn], u1 = Bus[kk][tn+1], u2 = Bus[kk][tn+2], u3 = Bus[kk][tn+3];
            accg[0][0] += a0*g0; accg[0][1] += a0*g1; accg[0][2] += a0*g2; accg[0][3] += a0*g3;
            accg[1][0] += a1*g0; accg[1][1] += a1*g1; accg[1][2] += a1*g2; accg[1][3] += a1*g3;
            accg[2][0] += a2*g0; accg[2][1] += a2*g1; accg[2][2] += a2*g2; accg[2][3] += a2*g3;
            accg[3][0] += a3*g0; accg[3][1] += a3*g1; accg[3][2] += a3*g2; accg[3][3] += a3*g3;
            accu[0][0] += a0*u0; accu[0][1] += a0*u1; accu[0][2] += a0*u2; accu[0][3] += a0*u3;
            accu[1][0] += a1*u0; accu[1][1] += a1*u1; accu[1][2] += a1*u2; accu[1][3] += a1*u3;
            accu[2][0] += a2*u0; accu[2][1] += a2*u1; accu[2][2] += a2*u2; accu[2][3] += a2*u3;
            accu[3][0] += a3*u0; accu[3][1] += a3*u1; accu[3][2] += a3*u2; accu[3][3] += a3*u3;
        }
        __syncthreads();
    }
    #pragma unroll
    for (int i = 0; i < 4; i++)
        #pragma unroll
        for (int j = 0; j < 4; j++) {
            float g = accg[i][j];
            float s = g / (1.f + expf(-g));     // silu
            Cact[(size_t)(m0 + tm + i) * N + n0 + tn + j] = s * accu[i][j];
        }
}

// ------------------------------------------------------------------
// LoRA: t16[row, c] = sum_k h[row,k] * la[c,k]     (la is [16, 2048])
__global__ __launch_bounds__(256) void lora_a_kernel(const float* __restrict__ h,
                                                     const float* __restrict__ la,
                                                     float* __restrict__ t16) {
    int r = threadIdx.x >> 4;   // local row 0..15
    int c = threadIdx.x & 15;   // rank idx
    int row = blockIdx.x * 16 + r;
    const float4* hr = (const float4*)(h + (size_t)row * D_);
    const float4* lr = (const float4*)(la + (size_t)c * D_);
    float acc = 0.f;
    #pragma unroll 4
    for (int i = 0; i < D_/4; i++) {
        float4 a = hr[i], b = lr[i];
        acc += a.x*b.x + a.y*b.y + a.z*b.z + a.w*b.w;
    }
    t16[(size_t)row * R_ + c] = acc;
}

// out[row, d] += 2 * sum_r t16[row,r] * lb[d, r]   (lb is [N, 16])
__global__ __launch_bounds__(256) void lora_b_kernel(const float* __restrict__ t16,
                                                     const float* __restrict__ lb,
                                                     float* __restrict__ out, int N) {
    int row = blockIdx.x;
    __shared__ float ts[R_];
    if (threadIdx.x < R_) ts[threadIdx.x] = t16[(size_t)row * R_ + threadIdx.x];
    __syncthreads();
    for (int d = threadIdx.x; d < N; d += 256) {
        const float4* lbr = (const float4*)(lb + (size_t)d * R_);
        float acc = 0.f;
        #pragma unroll
        for (int r4 = 0; r4 < 4; r4++) {
            float4 v = lbr[r4];
            acc += v.x*ts[r4*4] + v.y*ts[r4*4+1] + v.z*ts[r4*4+2] + v.w*ts[r4*4+3];
        }
        out[(size_t)row * N + d] += 2.0f * acc;
    }
}

// ------------------------------------------------------------------
// RoPE in-place: x is [BS, nh, 128]; pos = tok % S; LLaMA rotate_half
__global__ void rope_kernel(float* __restrict__ x, int nh) {
    int tok = blockIdx.x;
    int hh  = blockIdx.y;
    int t   = threadIdx.x;                 // 0..63
    int pos = tok & (S_ - 1);
    // inv_freq = theta^(-t/64);  ln(500000) = 13.122363377404328
    float inv = expf(-(float)t * (13.122363377404328f / 64.0f));
    float f = (float)pos * inv;
    float c = cosf(f), si = sinf(f);
    float* base = x + ((size_t)tok * nh + hh) * HD_;
    float x0 = base[t], x1 = base[t + 64];
    base[t]      = x0 * c - x1 * si;
    base[t + 64] = x1 * c + x0 * si;
}

// ------------------------------------------------------------------
// attention: one block per (q-row, head, batch); causal + key-padding mask
__global__ __launch_bounds__(256) void attn_kernel(const float* __restrict__ q,
                                                   const float* __restrict__ kk,
                                                   const float* __restrict__ vv,
                                                   const int* __restrict__ am,
                                                   float* __restrict__ o) {
    int qi = blockIdx.x, hh = blockIdx.y, b = blockIdx.z;
    int kvh = hh >> 2;                    // H/KV = 4
    int t = threadIdx.x;
    __shared__ float qrow[HD_];
    __shared__ float sc[S_];
    __shared__ float red[4];
    if (t < HD_) qrow[t] = q[(((size_t)b * S_ + qi) * H_ + hh) * HD_ + t];
    __syncthreads();

    const float4* q4 = (const float4*)qrow;
    float lmax = -1e30f;
    for (int j = t; j <= qi; j += 256) {
        float s;
        if (am[b * S_ + j]) {
            const float4* kr = (const float4*)(kk + (((size_t)b * S_ + j) * KV_ + kvh) * HD_);
            s = 0.f;
            #pragma unroll
            for (int ii = 0; ii < HD_/4; ii++) {
                float4 a = q4[ii], bb = kr[ii];
                s += a.x*bb.x + a.y*bb.y + a.z*bb.z + a.w*bb.w;
            }
            s *= 0.08838834764831845f;    // 1/sqrt(128)
        } else s = -1e9f;
        sc[j] = s;
        lmax = fmaxf(lmax, s);
    }
    for (int off = 32; off; off >>= 1) lmax = fmaxf(lmax, __shfl_down(lmax, off));
    if ((t & 63) == 0) red[t >> 6] = lmax;
    __syncthreads();
    float gmax = fmaxf(fmaxf(red[0], red[1]), fmaxf(red[2], red[3]));

    float lsum = 0.f;
    for (int j = t; j <= qi; j += 256) {
        float p = __expf(sc[j] - gmax);
        sc[j] = p;
        lsum += p;
    }
    __syncthreads();                      // all gmax reads + sc writes done
    for (int off = 32; off; off >>= 1) lsum += __shfl_down(lsum, off);
    if ((t & 63) == 0) red[t >> 6] = lsum;
    __syncthreads();
    float inv = 1.0f / (red[0] + red[1] + red[2] + red[3]);

    if (t < HD_) {
        float acc = 0.f;
        for (int j = 0; j <= qi; j++)
            acc += sc[j] * vv[(((size_t)b * S_ + j) * KV_ + kvh) * HD_ + t];
        o[(((size_t)b * S_ + qi) * H_ + hh) * HD_ + t] = acc * inv;
    }
}

// ------------------------------------------------------------------
// final masked mean-pool: out[b,d] = sum_s m*h / max(sum m, 1e-9)
__global__ __launch_bounds__(256) void pool_kernel(const float* __restrict__ h,
                                                   const int* __restrict__ am,
                                                   float* __restrict__ out) {
    int b = blockIdx.y;
    int d = blockIdx.x * 256 + threadIdx.x;
    float acc = 0.f, ms = 0.f;
    for (int s = 0; s < S_; s++) {
        float mm = (float)am[b * S_ + s];
        ms  += mm;
        acc += mm * h[((size_t)b * S_ + s) * D_ + d];
    }
    out[(size_t)b * D_ + d] = acc / fmaxf(ms, 1e-9f);
}

// ------------------------------------------------------------------
extern "C" void kernel_launch(void* const* d_in, const int* in_sizes, int n_in,
                              void* d_out, int out_size, void* d_ws, size_t ws_size,
                              hipStream_t stream) {
    const float* embed = (const float*)d_in[0];
    const float* wq    = (const float*)d_in[1];
    const float* wk    = (const float*)d_in[2];
    const float* wv    = (const float*)d_in[3];
    const float* wo    = (const float*)d_in[4];
    const float* laq   = (const float*)d_in[5];
    const float* lbq   = (const float*)d_in[6];
    const float* lav   = (const float*)d_in[7];
    const float* lbv   = (const float*)d_in[8];
    const float* wg    = (const float*)d_in[9];
    const float* wu    = (const float*)d_in[10];
    const float* wd    = (const float*)d_in[11];
    const float* n1    = (const float*)d_in[12];
    const float* n2    = (const float*)d_in[13];
    const float* nf    = (const float*)d_in[14];
    const int*   ids   = (const int*)d_in[15];
    const int*   am    = (const int*)d_in[16];
    float* out = (float*)d_out;

    float* ws  = (float*)d_ws;
    float* x   = ws;                       // [4096, 2048]
    float* h   = x + (size_t)BS_ * D_;     // [4096, 2048]
    float* big = h + (size_t)BS_ * D_;     // 33.55M floats, multi-purpose
    float* q   = big;                      // [4096, 2048]
    float* o   = big + (size_t)BS_ * D_;   // [4096, 2048]
    float* kb  = o   + (size_t)BS_ * D_;   // [4096, 512]
    float* vb  = kb  + (size_t)BS_ * KV_ * HD_;
    float* t16 = vb  + (size_t)BS_ * KV_ * HD_;
    float* act = big;                      // [4096, 8192] reuses q/o/k/v space

    embed_kernel<<<BS_, 256, 0, stream>>>(embed, ids, x);

    for (int l = 0; l < NL_; l++) {
        const float* wql = wq + (size_t)l * D_ * D_;
        const float* wkl = wk + (size_t)l * D_ * (KV_*HD_);
        const float* wvl = wv + (size_t)l * D_ * (KV_*HD_);
        const float* wol = wo + (size_t)l * D_ * D_;
        const float* wgl = wg + (size_t)l * D_ * F_;
        const float* wul = wu + (size_t)l * D_ * F_;
        const float* wdl = wd + (size_t)l * F_ * D_;

        rmsnorm_kernel<<<BS_, 256, 0, stream>>>(x, n1 + (size_t)l * D_, h);

        gemm_f32<0><<<dim3(D_/TN, BS_/TM), 256, 0, stream>>>(h, wql, q, BS_, D_, D_);
        lora_a_kernel<<<BS_/16, 256, 0, stream>>>(h, laq + (size_t)l * R_ * D_, t16);
        lora_b_kernel<<<BS_, 256, 0, stream>>>(t16, lbq + (size_t)l * D_ * R_, q, D_);

        gemm_f32<0><<<dim3((KV_*HD_)/TN, BS_/TM), 256, 0, stream>>>(h, wkl, kb, BS_, KV_*HD_, D_);
        gemm_f32<0><<<dim3((KV_*HD_)/TN, BS_/TM), 256, 0, stream>>>(h, wvl, vb, BS_, KV_*HD_, D_);
        lora_a_kernel<<<BS_/16, 256, 0, stream>>>(h, lav + (size_t)l * R_ * D_, t16);
        lora_b_kernel<<<BS_, 256, 0, stream>>>(t16, lbv + (size_t)l * (KV_*HD_) * R_, vb, KV_*HD_);

        rope_kernel<<<dim3(BS_, H_),  64, 0, stream>>>(q,  H_);
        rope_kernel<<<dim3(BS_, KV_), 64, 0, stream>>>(kb, KV_);

        attn_kernel<<<dim3(S_, H_, B_), 256, 0, stream>>>(q, kb, vb, am, o);

        gemm_f32<1><<<dim3(D_/TN, BS_/TM), 256, 0, stream>>>(o, wol, x, BS_, D_, D_);

        rmsnorm_kernel<<<BS_, 256, 0, stream>>>(x, n2 + (size_t)l * D_, h);
        gemm_gateup<<<dim3(F_/TN, BS_/TM), 256, 0, stream>>>(h, wgl, wul, act, BS_, F_, D_);
        gemm_f32<1><<<dim3(D_/TN, BS_/TM), 256, 0, stream>>>(act, wdl, x, BS_, D_, F_);
    }

    rmsnorm_kernel<<<BS_, 256, 0, stream>>>(x, nf, h);
    pool_kernel<<<dim3(D_/256, B_), 256, 0, stream>>>(h, am, out);
}

// Round 2
// 10217.872 us; speedup vs baseline: 2.4048x; 2.4048x over previous
//
#include <hip/hip_runtime.h>
#include <math.h>

#define B_  4
#define S_  1024
#define D_  2048
#define NL_ 2
#define H_  16
#define KV_ 4
#define F_  8192
#define R_  16
#define HD_ 128
#define BS_ (B_*S_)   // 4096 tokens

typedef unsigned short u16;
typedef __attribute__((ext_vector_type(8))) __bf16 bf16x8;
typedef __attribute__((ext_vector_type(4))) float  f32x4;

__device__ __forceinline__ u16 f2bf(float f) {
    unsigned x = __float_as_uint(f);
    unsigned r = (x + 0x7fffu + ((x >> 16) & 1u)) >> 16;   // RNE
    return (u16)r;
}
__device__ __forceinline__ float bf2f(u16 u) {
    return __uint_as_float(((unsigned)u) << 16);
}

// async global->LDS, 16B per lane. LDS dest must be linear (base + lane*16).
__device__ __forceinline__ void gload16(const void* g, void* l) {
    __builtin_amdgcn_global_load_lds((const __attribute__((address_space(1))) void*)g,
                                     (__attribute__((address_space(3))) void*)l, 16, 0, 0);
}

// ------------------------------------------------------------------
// embedding gather: x[tok,:] = embed[ids[tok],:]
__global__ void embed_kernel(const float* __restrict__ embed,
                             const int* __restrict__ ids,
                             float* __restrict__ x) {
    int tok = blockIdx.x;
    int id  = ids[tok];
    const float4* src = (const float4*)(embed + (size_t)id * D_);
    float4*       dst = (float4*)(x + (size_t)tok * D_);
    for (int i = threadIdx.x; i < D_/4; i += blockDim.x) dst[i] = src[i];
}

// ------------------------------------------------------------------
// rmsnorm per row of 2048; OUTBF=1 -> bf16 output, else f32
template<int OUTBF>
__global__ __launch_bounds__(256) void rmsnorm_kernel(const float* __restrict__ x,
                                                      const float* __restrict__ w,
                                                      void* __restrict__ out) {
    int row = blockIdx.x;
    const float4* xr = (const float4*)(x + (size_t)row * D_);
    float ss = 0.f;
    for (int i = threadIdx.x; i < D_/4; i += 256) {
        float4 v = xr[i];
        ss += v.x*v.x + v.y*v.y + v.z*v.z + v.w*v.w;
    }
    __shared__ float red[4];
    for (int off = 32; off; off >>= 1) ss += __shfl_down(ss, off);
    if ((threadIdx.x & 63) == 0) red[threadIdx.x >> 6] = ss;
    __syncthreads();
    float tot = red[0] + red[1] + red[2] + red[3];
    float scale = rsqrtf(tot / (float)D_ + 1e-5f);
    const float4* w4 = (const float4*)w;
    for (int i = threadIdx.x; i < D_/4; i += 256) {
        float4 v = xr[i], g = w4[i];
        float a = v.x*scale*g.x, b = v.y*scale*g.y, c = v.z*scale*g.z, d = v.w*scale*g.w;
        if (OUTBF) {
            ushort4 o; o.x = f2bf(a); o.y = f2bf(b); o.z = f2bf(c); o.w = f2bf(d);
            ((ushort4*)((u16*)out + (size_t)row * D_))[i] = o;
        } else {
            float4 o; o.x = a; o.y = b; o.z = c; o.w = d;
            ((float4*)((float*)out + (size_t)row * D_))[i] = o;
        }
    }
}

// ------------------------------------------------------------------
// transpose + f32->bf16: in [K][N] f32 row-major  ->  out [N][K] bf16 row-major
__global__ __launch_bounds__(256) void convt_kernel(const float* __restrict__ in,
                                                    u16* __restrict__ outT,
                                                    int K, int N) {
    __shared__ float tile[32][33];
    int k0 = blockIdx.y * 32, n0 = blockIdx.x * 32;
    int t = threadIdx.x;
    int r = t >> 3, c4 = (t & 7) * 4;
    float4 v = *(const float4*)(in + (size_t)(k0 + r) * N + n0 + c4);
    tile[r][c4] = v.x; tile[r][c4+1] = v.y; tile[r][c4+2] = v.z; tile[r][c4+3] = v.w;
    __syncthreads();
    int n = t >> 3, kc = (t & 7) * 4;
    ushort4 o;
    o.x = f2bf(tile[kc][n]);   o.y = f2bf(tile[kc+1][n]);
    o.z = f2bf(tile[kc+2][n]); o.w = f2bf(tile[kc+3][n]);
    *(ushort4*)(outT + (size_t)(n0 + n) * K + k0 + kc) = o;
}

// ------------------------------------------------------------------
// MFMA GEMM, B transposed: C[M,N] (+)= A[M,K](bf16) @ Bt[N,K](bf16)^T, C f32
// 128x128 tile, BK=64, 4 waves (2x2), wave tile 64x64, XOR-swizzled LDS.
template<int ACC>
__global__ __launch_bounds__(256) void gemm_bt(const u16* __restrict__ A,
                                               const u16* __restrict__ Bt,
                                               float* __restrict__ C,
                                               int N, int K) {
    __shared__ __align__(16) u16 As[128*64];
    __shared__ __align__(16) u16 Bs[128*64];
    int tid = threadIdx.x, lane = tid & 63;
    int wid = tid >> 6, wm = wid >> 1, wn = wid & 1;
    int m0 = blockIdx.y * 128, n0 = blockIdx.x * 128;
    const u16* Ab = A  + (size_t)m0 * K;
    const u16* Bb = Bt + (size_t)n0 * K;
    f32x4 acc[4][4] = {};
    for (int k0 = 0; k0 < K; k0 += 64) {
        #pragma unroll
        for (int qq = 0; qq < 4; qq++) {
            int u = qq * 256 + tid;
            int row = u >> 3, cu = u & 7, scu = cu ^ (row & 7);
            size_t goff = (size_t)row * K + k0 + scu * 8;
            gload16(Ab + goff, (char*)As + u * 16);
            gload16(Bb + goff, (char*)Bs + u * 16);
        }
        __syncthreads();
        #pragma unroll
        for (int kk = 0; kk < 2; kk++) {
            int cu = kk * 4 + (lane >> 4);
            bf16x8 af[4], bfr[4];
            #pragma unroll
            for (int i = 0; i < 4; i++) {
                int ar = wm * 64 + i * 16 + (lane & 15);
                af[i]  = *(const bf16x8*)((const char*)As + (((ar << 3) | (cu ^ (ar & 7))) << 4));
                int br = wn * 64 + i * 16 + (lane & 15);
                bfr[i] = *(const bf16x8*)((const char*)Bs + (((br << 3) | (cu ^ (br & 7))) << 4));
            }
            #pragma unroll
            for (int i = 0; i < 4; i++)
                #pragma unroll
                for (int j = 0; j < 4; j++)
                    acc[i][j] = __builtin_amdgcn_mfma_f32_16x16x32_bf16(af[i], bfr[j], acc[i][j], 0, 0, 0);
        }
        __syncthreads();
    }
    int r0 = (lane >> 4) * 4, c0 = lane & 15;
    #pragma unroll
    for (int i = 0; i < 4; i++)
        #pragma unroll
        for (int j = 0; j < 4; j++) {
            int row = m0 + wm * 64 + i * 16 + r0;
            int col = n0 + wn * 64 + j * 16 + c0;
            float* cp = C + (size_t)row * N + col;
            #pragma unroll
            for (int r = 0; r < 4; r++) {
                if (ACC) cp[(size_t)r * N] += acc[i][j][r];
                else     cp[(size_t)r * N] = acc[i][j][r];
            }
        }
}

// ------------------------------------------------------------------
// fused gate/up MFMA GEMM: act = silu(A@G) * (A@U), all operands bf16-T.
// 128x64 tile (per operand), BK=64, 4 waves (2x2), wave tile 64x32.
__global__ __launch_bounds__(256) void gemm_gateup_bt(const u16* __restrict__ A,
                                                      const u16* __restrict__ Gt,
                                                      const u16* __restrict__ Ut,
                                                      u16* __restrict__ act,
                                                      int N, int K) {
    __shared__ __align__(16) u16 As[128*64];
    __shared__ __align__(16) u16 Gs[64*64];
    __shared__ __align__(16) u16 Us[64*64];
    int tid = threadIdx.x, lane = tid & 63;
    int wid = tid >> 6, wm = wid >> 1, wn = wid & 1;
    int m0 = blockIdx.y * 128, n0 = blockIdx.x * 64;
    const u16* Ab = A  + (size_t)m0 * K;
    const u16* Gb = Gt + (size_t)n0 * K;
    const u16* Ub = Ut + (size_t)n0 * K;
    f32x4 ag[4][2] = {}, au[4][2] = {};
    for (int k0 = 0; k0 < K; k0 += 64) {
        #pragma unroll
        for (int qq = 0; qq < 4; qq++) {
            int u = qq * 256 + tid;
            int row = u >> 3, cu = u & 7, scu = cu ^ (row & 7);
            gload16(Ab + (size_t)row * K + k0 + scu * 8, (char*)As + u * 16);
        }
        #pragma unroll
        for (int qq = 0; qq < 2; qq++) {
            int u = qq * 256 + tid;
            int row = u >> 3, cu = u & 7, scu = cu ^ (row & 7);
            size_t goff = (size_t)row * K + k0 + scu * 8;
            gload16(Gb + goff, (char*)Gs + u * 16);
            gload16(Ub + goff, (char*)Us + u * 16);
        }
        __syncthreads();
        #pragma unroll
        for (int kk = 0; kk < 2; kk++) {
            int cu = kk * 4 + (lane >> 4);
            bf16x8 af[4], gf[2], uf[2];
            #pragma unroll
            for (int i = 0; i < 4; i++) {
                int ar = wm * 64 + i * 16 + (lane & 15);
                af[i] = *(const bf16x8*)((const char*)As + (((ar << 3) | (cu ^ (ar & 7))) << 4));
            }
            #pragma unroll
            for (int j = 0; j < 2; j++) {
                int br = wn * 32 + j * 16 + (lane & 15);
                int off = ((br << 3) | (cu ^ (br & 7))) << 4;
                gf[j] = *(const bf16x8*)((const char*)Gs + off);
                uf[j] = *(const bf16x8*)((const char*)Us + off);
            }
            #pragma unroll
            for (int i = 0; i < 4; i++)
                #pragma unroll
                for (int j = 0; j < 2; j++) {
                    ag[i][j] = __builtin_amdgcn_mfma_f32_16x16x32_bf16(af[i], gf[j], ag[i][j], 0, 0, 0);
                    au[i][j] = __builtin_amdgcn_mfma_f32_16x16x32_bf16(af[i], uf[j], au[i][j], 0, 0, 0);
                }
        }
        __syncthreads();
    }
    int r0 = (lane >> 4) * 4, c0 = lane & 15;
    #pragma unroll
    for (int i = 0; i < 4; i++)
        #pragma unroll
        for (int j = 0; j < 2; j++) {
            int col = n0 + wn * 32 + j * 16 + c0;
            #pragma unroll
            for (int r = 0; r < 4; r++) {
                int row = m0 + wm * 64 + i * 16 + r0 + r;
                float g = ag[i][j][r], u = au[i][j][r];
                float s = g / (1.f + __expf(-g));
                act[(size_t)row * N + col] = f2bf(s * u);
            }
        }
}

// ------------------------------------------------------------------
// LoRA: t16[row, c] = sum_k h[row,k] * la[c,k]     (la is [16, 2048] f32)
__global__ __launch_bounds__(256) void lora_a_kernel(const u16* __restrict__ h,
                                                     const float* __restrict__ la,
                                                     float* __restrict__ t16) {
    int r = threadIdx.x >> 4;   // local row 0..15
    int c = threadIdx.x & 15;   // rank idx
    int row = blockIdx.x * 16 + r;
    const ushort4* hr = (const ushort4*)(h + (size_t)row * D_);
    const float4* lr = (const float4*)(la + (size_t)c * D_);
    float acc = 0.f;
    #pragma unroll 4
    for (int i = 0; i < D_/4; i++) {
        ushort4 a = hr[i]; float4 b = lr[i];
        acc += bf2f(a.x)*b.x + bf2f(a.y)*b.y + bf2f(a.z)*b.z + bf2f(a.w)*b.w;
    }
    t16[(size_t)row * R_ + c] = acc;
}

// out[row, d] += 2 * sum_r t16[row,r] * lb[d, r]   (lb is [N, 16])
__global__ __launch_bounds__(256) void lora_b_kernel(const float* __restrict__ t16,
                                                     const float* __restrict__ lb,
                                                     float* __restrict__ out, int N) {
    int row = blockIdx.x;
    __shared__ float ts[R_];
    if (threadIdx.x < R_) ts[threadIdx.x] = t16[(size_t)row * R_ + threadIdx.x];
    __syncthreads();
    for (int d = threadIdx.x; d < N; d += 256) {
        const float4* lbr = (const float4*)(lb + (size_t)d * R_);
        float acc = 0.f;
        #pragma unroll
        for (int r4 = 0; r4 < 4; r4++) {
            float4 v = lbr[r4];
            acc += v.x*ts[r4*4] + v.y*ts[r4*4+1] + v.z*ts[r4*4+2] + v.w*ts[r4*4+3];
        }
        out[(size_t)row * N + d] += 2.0f * acc;
    }
}

// ------------------------------------------------------------------
// RoPE in-place: x is [BS, nh, 128]; pos = tok % S; LLaMA rotate_half
__global__ void rope_kernel(float* __restrict__ x, int nh) {
    int tok = blockIdx.x;
    int hh  = blockIdx.y;
    int t   = threadIdx.x;                 // 0..63
    int pos = tok & (S_ - 1);
    float inv = expf(-(float)t * (13.122363377404328f / 64.0f));
    float f = (float)pos * inv;
    float c = cosf(f), si = sinf(f);
    float* base = x + ((size_t)tok * nh + hh) * HD_;
    float x0 = base[t], x1 = base[t + 64];
    base[t]      = x0 * c - x1 * si;
    base[t + 64] = x1 * c + x0 * si;
}

// ------------------------------------------------------------------
// attention: one block per (q-row, head, batch); causal + key-padding mask
__global__ __launch_bounds__(256) void attn_kernel(const float* __restrict__ q,
                                                   const float* __restrict__ kk,
                                                   const float* __restrict__ vv,
                                                   const int* __restrict__ am,
                                                   u16* __restrict__ o) {
    int qi = blockIdx.x, hh = blockIdx.y, b = blockIdx.z;
    int kvh = hh >> 2;                    // H/KV = 4
    int t = threadIdx.x;
    __shared__ float qrow[HD_];
    __shared__ float sc[S_];
    __shared__ float red[4];
    __shared__ float pv[2][HD_];
    if (t < HD_) qrow[t] = q[(((size_t)b * S_ + qi) * H_ + hh) * HD_ + t];
    __syncthreads();

    const float4* q4 = (const float4*)qrow;
    float lmax = -1e30f;
    for (int j = t; j <= qi; j += 256) {
        float s;
        if (am[b * S_ + j]) {
            const float4* kr = (const float4*)(kk + (((size_t)b * S_ + j) * KV_ + kvh) * HD_);
            s = 0.f;
            #pragma unroll
            for (int ii = 0; ii < HD_/4; ii++) {
                float4 a = q4[ii], bb = kr[ii];
                s += a.x*bb.x + a.y*bb.y + a.z*bb.z + a.w*bb.w;
            }
            s *= 0.08838834764831845f;    // 1/sqrt(128)
        } else s = -1e9f;
        sc[j] = s;
        lmax = fmaxf(lmax, s);
    }
    for (int off = 32; off; off >>= 1) lmax = fmaxf(lmax, __shfl_down(lmax, off));
    if ((t & 63) == 0) red[t >> 6] = lmax;
    __syncthreads();
    float gmax = fmaxf(fmaxf(red[0], red[1]), fmaxf(red[2], red[3]));

    float lsum = 0.f;
    for (int j = t; j <= qi; j += 256) {
        float p = __expf(sc[j] - gmax);
        sc[j] = p;
        lsum += p;
    }
    __syncthreads();
    for (int off = 32; off; off >>= 1) lsum += __shfl_down(lsum, off);
    if ((t & 63) == 0) red[t >> 6] = lsum;
    __syncthreads();
    float inv = 1.0f / (red[0] + red[1] + red[2] + red[3]);

    // PV with 2-way j split over 256 threads
    int d = t & 127, js = t >> 7;
    float acc = 0.f;
    for (int j = js; j <= qi; j += 2)
        acc += sc[j] * vv[(((size_t)b * S_ + j) * KV_ + kvh) * HD_ + d];
    pv[js][d] = acc;
    __syncthreads();
    if (t < HD_)
        o[(((size_t)b * S_ + qi) * H_ + hh) * HD_ + t] = f2bf((pv[0][t] + pv[1][t]) * inv);
}

// ------------------------------------------------------------------
// final masked mean-pool
__global__ __launch_bounds__(256) void pool_kernel(const float* __restrict__ h,
                                                   const int* __restrict__ am,
                                                   float* __restrict__ out) {
    int b = blockIdx.y;
    int d = blockIdx.x * 256 + threadIdx.x;
    float acc = 0.f, ms = 0.f;
    for (int s = 0; s < S_; s++) {
        float mm = (float)am[b * S_ + s];
        ms  += mm;
        acc += mm * h[((size_t)b * S_ + s) * D_ + d];
    }
    out[(size_t)b * D_ + d] = acc / fmaxf(ms, 1e-9f);
}

// ------------------------------------------------------------------
extern "C" void kernel_launch(void* const* d_in, const int* in_sizes, int n_in,
                              void* d_out, int out_size, void* d_ws, size_t ws_size,
                              hipStream_t stream) {
    const float* embed = (const float*)d_in[0];
    const float* wq    = (const float*)d_in[1];
    const float* wk    = (const float*)d_in[2];
    const float* wv    = (const float*)d_in[3];
    const float* wo    = (const float*)d_in[4];
    const float* laq   = (const float*)d_in[5];
    const float* lbq   = (const float*)d_in[6];
    const float* lav   = (const float*)d_in[7];
    const float* lbv   = (const float*)d_in[8];
    const float* wg    = (const float*)d_in[9];
    const float* wu    = (const float*)d_in[10];
    const float* wd    = (const float*)d_in[11];
    const float* n1    = (const float*)d_in[12];
    const float* n2    = (const float*)d_in[13];
    const float* nf    = (const float*)d_in[14];
    const int*   ids   = (const int*)d_in[15];
    const int*   am    = (const int*)d_in[16];
    float* out = (float*)d_out;

    char* base = (char*)d_ws;
    float* x   = (float*)base;                          // 33.55 MB f32
    u16*   hbf = (u16*)(base + 33554432);               // 16.78 MB bf16
    u16*   obf = (u16*)(base + 50331648);               // 16.78 MB bf16
    char*  Rg  = base + 67108864;                       // 67.11 MB multi-purpose
    float* q   = (float*)Rg;                            // 33.55 MB f32
    float* kb  = (float*)(Rg + 33554432);               // 8.39 MB f32
    float* vb  = (float*)(Rg + 41943040);               // 8.39 MB f32
    u16*   act = (u16*)Rg;                              // 67.11 MB bf16 (after attn)
    float* hf  = (float*)Rg;                            // final norm f32 (after MLP)
    float* t16 = (float*)(base + 134217728);            // 0.26 MB
    u16*   wT0 = (u16*)(base + 134479872);              // 33.55 MB bf16
    u16*   wT1 = (u16*)(base + 168034304);              // 33.55 MB bf16
    // total ~201.6 MB

    embed_kernel<<<BS_, 256, 0, stream>>>(embed, ids, x);

    for (int l = 0; l < NL_; l++) {
        const float* wql = wq + (size_t)l * D_ * D_;
        const float* wkl = wk + (size_t)l * D_ * (KV_*HD_);
        const float* wvl = wv + (size_t)l * D_ * (KV_*HD_);
        const float* wol = wo + (size_t)l * D_ * D_;
        const float* wgl = wg + (size_t)l * D_ * F_;
        const float* wul = wu + (size_t)l * D_ * F_;
        const float* wdl = wd + (size_t)l * F_ * D_;

        rmsnorm_kernel<1><<<BS_, 256, 0, stream>>>(x, n1 + (size_t)l * D_, hbf);

        // q projection
        convt_kernel<<<dim3(D_/32, D_/32), 256, 0, stream>>>(wql, wT0, D_, D_);
        gemm_bt<0><<<dim3(D_/128, BS_/128), 256, 0, stream>>>(hbf, wT0, q, D_, D_);
        lora_a_kernel<<<BS_/16, 256, 0, stream>>>(hbf, laq + (size_t)l * R_ * D_, t16);
        lora_b_kernel<<<BS_, 256, 0, stream>>>(t16, lbq + (size_t)l * D_ * R_, q, D_);

        // k, v projections
        convt_kernel<<<dim3((KV_*HD_)/32, D_/32), 256, 0, stream>>>(wkl, wT0, D_, KV_*HD_);
        gemm_bt<0><<<dim3((KV_*HD_)/128, BS_/128), 256, 0, stream>>>(hbf, wT0, kb, KV_*HD_, D_);
        convt_kernel<<<dim3((KV_*HD_)/32, D_/32), 256, 0, stream>>>(wvl, wT0, D_, KV_*HD_);
        gemm_bt<0><<<dim3((KV_*HD_)/128, BS_/128), 256, 0, stream>>>(hbf, wT0, vb, KV_*HD_, D_);
        lora_a_kernel<<<BS_/16, 256, 0, stream>>>(hbf, lav + (size_t)l * R_ * D_, t16);
        lora_b_kernel<<<BS_, 256, 0, stream>>>(t16, lbv + (size_t)l * (KV_*HD_) * R_, vb, KV_*HD_);

        rope_kernel<<<dim3(BS_, H_),  64, 0, stream>>>(q,  H_);
        rope_kernel<<<dim3(BS_, KV_), 64, 0, stream>>>(kb, KV_);

        attn_kernel<<<dim3(S_, H_, B_), 256, 0, stream>>>(q, kb, vb, am, obf);

        // o projection (accumulate into residual x)
        convt_kernel<<<dim3(D_/32, D_/32), 256, 0, stream>>>(wol, wT0, D_, D_);
        gemm_bt<1><<<dim3(D_/128, BS_/128), 256, 0, stream>>>(obf, wT0, x, D_, D_);

        // MLP
        rmsnorm_kernel<1><<<BS_, 256, 0, stream>>>(x, n2 + (size_t)l * D_, hbf);
        convt_kernel<<<dim3(F_/32, D_/32), 256, 0, stream>>>(wgl, wT0, D_, F_);
        convt_kernel<<<dim3(F_/32, D_/32), 256, 0, stream>>>(wul, wT1, D_, F_);
        gemm_gateup_bt<<<dim3(F_/64, BS_/128), 256, 0, stream>>>(hbf, wT0, wT1, act, F_, D_);
        convt_kernel<<<dim3(D_/32, F_/32), 256, 0, stream>>>(wdl, wT0, F_, D_);
        gemm_bt<1><<<dim3(D_/128, BS_/128), 256, 0, stream>>>(act, wT0, x, D_, F_);
    }

    rmsnorm_kernel<0><<<BS_, 256, 0, stream>>>(x, nf, hf);
    pool_kernel<<<dim3(D_/256, B_), 256, 0, stream>>>(hf, am, out);
}

// Round 3
// 2189.897 us; speedup vs baseline: 11.2208x; 4.6659x over previous
//
#include <hip/hip_runtime.h>
#include <math.h>

#define B_  4
#define S_  1024
#define D_  2048
#define NL_ 2
#define H_  16
#define KV_ 4
#define F_  8192
#define R_  16
#define HD_ 128
#define BS_ (B_*S_)   // 4096 tokens
#define QBLK 64
#define KBLK 64

typedef unsigned short u16;
typedef __attribute__((ext_vector_type(8))) __bf16 bf16x8;
typedef __attribute__((ext_vector_type(4))) float  f32x4;

__device__ __forceinline__ u16 f2bf(float f) {
    unsigned x = __float_as_uint(f);
    unsigned r = (x + 0x7fffu + ((x >> 16) & 1u)) >> 16;   // RNE
    return (u16)r;
}
__device__ __forceinline__ float bf2f(u16 u) {
    return __uint_as_float(((unsigned)u) << 16);
}

// async global->LDS, 16B per lane. LDS dest must be linear (base + lane*16).
__device__ __forceinline__ void gload16(const void* g, void* l) {
    __builtin_amdgcn_global_load_lds((const __attribute__((address_space(1))) void*)g,
                                     (__attribute__((address_space(3))) void*)l, 16, 0, 0);
}

// ------------------------------------------------------------------
__global__ void embed_kernel(const float* __restrict__ embed,
                             const int* __restrict__ ids,
                             float* __restrict__ x) {
    int tok = blockIdx.x;
    int id  = ids[tok];
    const float4* src = (const float4*)(embed + (size_t)id * D_);
    float4*       dst = (float4*)(x + (size_t)tok * D_);
    for (int i = threadIdx.x; i < D_/4; i += blockDim.x) dst[i] = src[i];
}

// ------------------------------------------------------------------
template<int OUTBF>
__global__ __launch_bounds__(256) void rmsnorm_kernel(const float* __restrict__ x,
                                                      const float* __restrict__ w,
                                                      void* __restrict__ out) {
    int row = blockIdx.x;
    const float4* xr = (const float4*)(x + (size_t)row * D_);
    float ss = 0.f;
    for (int i = threadIdx.x; i < D_/4; i += 256) {
        float4 v = xr[i];
        ss += v.x*v.x + v.y*v.y + v.z*v.z + v.w*v.w;
    }
    __shared__ float red[4];
    for (int off = 32; off; off >>= 1) ss += __shfl_down(ss, off);
    if ((threadIdx.x & 63) == 0) red[threadIdx.x >> 6] = ss;
    __syncthreads();
    float tot = red[0] + red[1] + red[2] + red[3];
    float scale = rsqrtf(tot / (float)D_ + 1e-5f);
    const float4* w4 = (const float4*)w;
    for (int i = threadIdx.x; i < D_/4; i += 256) {
        float4 v = xr[i], g = w4[i];
        float a = v.x*scale*g.x, b = v.y*scale*g.y, c = v.z*scale*g.z, d = v.w*scale*g.w;
        if (OUTBF) {
            ushort4 o; o.x = f2bf(a); o.y = f2bf(b); o.z = f2bf(c); o.w = f2bf(d);
            ((ushort4*)((u16*)out + (size_t)row * D_))[i] = o;
        } else {
            float4 o; o.x = a; o.y = b; o.z = c; o.w = d;
            ((float4*)((float*)out + (size_t)row * D_))[i] = o;
        }
    }
}

// ------------------------------------------------------------------
// transpose + f32->bf16: in [K][N] f32 row-major  ->  out [N][K] bf16 row-major
__global__ __launch_bounds__(256) void convt_kernel(const float* __restrict__ in,
                                                    u16* __restrict__ outT,
                                                    int K, int N) {
    __shared__ float tile[32][33];
    int k0 = blockIdx.y * 32, n0 = blockIdx.x * 32;
    int t = threadIdx.x;
    int r = t >> 3, c4 = (t & 7) * 4;
    float4 v = *(const float4*)(in + (size_t)(k0 + r) * N + n0 + c4);
    tile[r][c4] = v.x; tile[r][c4+1] = v.y; tile[r][c4+2] = v.z; tile[r][c4+3] = v.w;
    __syncthreads();
    int n = t >> 3, kc = (t & 7) * 4;
    ushort4 o;
    o.x = f2bf(tile[kc][n]);   o.y = f2bf(tile[kc+1][n]);
    o.z = f2bf(tile[kc+2][n]); o.w = f2bf(tile[kc+3][n]);
    *(ushort4*)(outT + (size_t)(n0 + n) * K + k0 + kc) = o;
}

// ------------------------------------------------------------------
// MFMA GEMM, B transposed: C[M,N] (+)= A[M,K](bf16) @ Bt[N,K](bf16)^T, C f32
template<int ACC>
__global__ __launch_bounds__(256) void gemm_bt(const u16* __restrict__ A,
                                               const u16* __restrict__ Bt,
                                               float* __restrict__ C,
                                               int N, int K) {
    __shared__ __align__(16) u16 As[128*64];
    __shared__ __align__(16) u16 Bs[128*64];
    int tid = threadIdx.x, lane = tid & 63;
    int wid = tid >> 6, wm = wid >> 1, wn = wid & 1;
    int m0 = blockIdx.y * 128, n0 = blockIdx.x * 128;
    const u16* Ab = A  + (size_t)m0 * K;
    const u16* Bb = Bt + (size_t)n0 * K;
    f32x4 acc[4][4] = {};
    for (int k0 = 0; k0 < K; k0 += 64) {
        #pragma unroll
        for (int qq = 0; qq < 4; qq++) {
            int u = qq * 256 + tid;
            int row = u >> 3, cu = u & 7, scu = cu ^ (row & 7);
            size_t goff = (size_t)row * K + k0 + scu * 8;
            gload16(Ab + goff, (char*)As + u * 16);
            gload16(Bb + goff, (char*)Bs + u * 16);
        }
        __syncthreads();
        #pragma unroll
        for (int kk = 0; kk < 2; kk++) {
            int cu = kk * 4 + (lane >> 4);
            bf16x8 af[4], bfr[4];
            #pragma unroll
            for (int i = 0; i < 4; i++) {
                int ar = wm * 64 + i * 16 + (lane & 15);
                af[i]  = *(const bf16x8*)((const char*)As + (((ar << 3) | (cu ^ (ar & 7))) << 4));
                int br = wn * 64 + i * 16 + (lane & 15);
                bfr[i] = *(const bf16x8*)((const char*)Bs + (((br << 3) | (cu ^ (br & 7))) << 4));
            }
            #pragma unroll
            for (int i = 0; i < 4; i++)
                #pragma unroll
                for (int j = 0; j < 4; j++)
                    acc[i][j] = __builtin_amdgcn_mfma_f32_16x16x32_bf16(af[i], bfr[j], acc[i][j], 0, 0, 0);
        }
        __syncthreads();
    }
    int r0 = (lane >> 4) * 4, c0 = lane & 15;
    #pragma unroll
    for (int i = 0; i < 4; i++)
        #pragma unroll
        for (int j = 0; j < 4; j++) {
            int row = m0 + wm * 64 + i * 16 + r0;
            int col = n0 + wn * 64 + j * 16 + c0;
            float* cp = C + (size_t)row * N + col;
            #pragma unroll
            for (int r = 0; r < 4; r++) {
                if (ACC) cp[(size_t)r * N] += acc[i][j][r];
                else     cp[(size_t)r * N] = acc[i][j][r];
            }
        }
}

// ------------------------------------------------------------------
// fused gate/up MFMA GEMM: act = silu(A@G) * (A@U)
__global__ __launch_bounds__(256) void gemm_gateup_bt(const u16* __restrict__ A,
                                                      const u16* __restrict__ Gt,
                                                      const u16* __restrict__ Ut,
                                                      u16* __restrict__ act,
                                                      int N, int K) {
    __shared__ __align__(16) u16 As[128*64];
    __shared__ __align__(16) u16 Gs[64*64];
    __shared__ __align__(16) u16 Us[64*64];
    int tid = threadIdx.x, lane = tid & 63;
    int wid = tid >> 6, wm = wid >> 1, wn = wid & 1;
    int m0 = blockIdx.y * 128, n0 = blockIdx.x * 64;
    const u16* Ab = A  + (size_t)m0 * K;
    const u16* Gb = Gt + (size_t)n0 * K;
    const u16* Ub = Ut + (size_t)n0 * K;
    f32x4 ag[4][2] = {}, au[4][2] = {};
    for (int k0 = 0; k0 < K; k0 += 64) {
        #pragma unroll
        for (int qq = 0; qq < 4; qq++) {
            int u = qq * 256 + tid;
            int row = u >> 3, cu = u & 7, scu = cu ^ (row & 7);
            gload16(Ab + (size_t)row * K + k0 + scu * 8, (char*)As + u * 16);
        }
        #pragma unroll
        for (int qq = 0; qq < 2; qq++) {
            int u = qq * 256 + tid;
            int row = u >> 3, cu = u & 7, scu = cu ^ (row & 7);
            size_t goff = (size_t)row * K + k0 + scu * 8;
            gload16(Gb + goff, (char*)Gs + u * 16);
            gload16(Ub + goff, (char*)Us + u * 16);
        }
        __syncthreads();
        #pragma unroll
        for (int kk = 0; kk < 2; kk++) {
            int cu = kk * 4 + (lane >> 4);
            bf16x8 af[4], gf[2], uf[2];
            #pragma unroll
            for (int i = 0; i < 4; i++) {
                int ar = wm * 64 + i * 16 + (lane & 15);
                af[i] = *(const bf16x8*)((const char*)As + (((ar << 3) | (cu ^ (ar & 7))) << 4));
            }
            #pragma unroll
            for (int j = 0; j < 2; j++) {
                int br = wn * 32 + j * 16 + (lane & 15);
                int off = ((br << 3) | (cu ^ (br & 7))) << 4;
                gf[j] = *(const bf16x8*)((const char*)Gs + off);
                uf[j] = *(const bf16x8*)((const char*)Us + off);
            }
            #pragma unroll
            for (int i = 0; i < 4; i++)
                #pragma unroll
                for (int j = 0; j < 2; j++) {
                    ag[i][j] = __builtin_amdgcn_mfma_f32_16x16x32_bf16(af[i], gf[j], ag[i][j], 0, 0, 0);
                    au[i][j] = __builtin_amdgcn_mfma_f32_16x16x32_bf16(af[i], uf[j], au[i][j], 0, 0, 0);
                }
        }
        __syncthreads();
    }
    int r0 = (lane >> 4) * 4, c0 = lane & 15;
    #pragma unroll
    for (int i = 0; i < 4; i++)
        #pragma unroll
        for (int j = 0; j < 2; j++) {
            int col = n0 + wn * 32 + j * 16 + c0;
            #pragma unroll
            for (int r = 0; r < 4; r++) {
                int row = m0 + wm * 64 + i * 16 + r0 + r;
                float g = ag[i][j][r], u = au[i][j][r];
                float s = g / (1.f + __expf(-g));
                act[(size_t)row * N + col] = f2bf(s * u);
            }
        }
}

// ------------------------------------------------------------------
// LoRA
__global__ __launch_bounds__(256) void lora_a_kernel(const u16* __restrict__ h,
                                                     const float* __restrict__ la,
                                                     float* __restrict__ t16) {
    int r = threadIdx.x >> 4;
    int c = threadIdx.x & 15;
    int row = blockIdx.x * 16 + r;
    const ushort4* hr = (const ushort4*)(h + (size_t)row * D_);
    const float4* lr = (const float4*)(la + (size_t)c * D_);
    float acc = 0.f;
    #pragma unroll 4
    for (int i = 0; i < D_/4; i++) {
        ushort4 a = hr[i]; float4 b = lr[i];
        acc += bf2f(a.x)*b.x + bf2f(a.y)*b.y + bf2f(a.z)*b.z + bf2f(a.w)*b.w;
    }
    t16[(size_t)row * R_ + c] = acc;
}

__global__ __launch_bounds__(256) void lora_b_kernel(const float* __restrict__ t16,
                                                     const float* __restrict__ lb,
                                                     float* __restrict__ out, int N) {
    int row = blockIdx.x;
    __shared__ float ts[R_];
    if (threadIdx.x < R_) ts[threadIdx.x] = t16[(size_t)row * R_ + threadIdx.x];
    __syncthreads();
    for (int d = threadIdx.x; d < N; d += 256) {
        const float4* lbr = (const float4*)(lb + (size_t)d * R_);
        float acc = 0.f;
        #pragma unroll
        for (int r4 = 0; r4 < 4; r4++) {
            float4 v = lbr[r4];
            acc += v.x*ts[r4*4] + v.y*ts[r4*4+1] + v.z*ts[r4*4+2] + v.w*ts[r4*4+3];
        }
        out[(size_t)row * N + d] += 2.0f * acc;
    }
}

// ------------------------------------------------------------------
// fused RoPE + f32->bf16 conv, Q: [BS,H,128] f32 -> Qc [B][H][S][128] bf16
__global__ void qconv_rope(const float* __restrict__ q, u16* __restrict__ Qc) {
    int tok = blockIdx.x, h = blockIdx.y, t = threadIdx.x;   // t: 0..63
    int b = tok >> 10, s = tok & (S_ - 1);
    float inv = __expf(-(float)t * (13.122363377404328f / 64.0f));
    float f = (float)s * inv;
    float c = __cosf(f), si = __sinf(f);
    const float* src = q + ((size_t)tok * H_ + h) * HD_;
    float x0 = src[t], x1 = src[t + 64];
    u16* dst = Qc + (((size_t)(b * H_ + h)) * S_ + s) * HD_;
    dst[t]      = f2bf(x0 * c - x1 * si);
    dst[t + 64] = f2bf(x1 * c + x0 * si);
}

// K: [BS,KV,128] f32 -> Kc [B][KV][S][128] bf16 (with RoPE)
__global__ void kconv_rope(const float* __restrict__ k, u16* __restrict__ Kc) {
    int tok = blockIdx.x, h = blockIdx.y, t = threadIdx.x;
    int b = tok >> 10, s = tok & (S_ - 1);
    float inv = __expf(-(float)t * (13.122363377404328f / 64.0f));
    float f = (float)s * inv;
    float c = __cosf(f), si = __sinf(f);
    const float* src = k + ((size_t)tok * KV_ + h) * HD_;
    float x0 = src[t], x1 = src[t + 64];
    u16* dst = Kc + (((size_t)(b * KV_ + h)) * S_ + s) * HD_;
    dst[t]      = f2bf(x0 * c - x1 * si);
    dst[t + 64] = f2bf(x1 * c + x0 * si);
}

// V: [BS,KV,128] f32 -> Vt [B][KV][128][S] bf16 (transposed)
__global__ __launch_bounds__(256) void vconv_t(const float* __restrict__ vb,
                                               u16* __restrict__ Vt) {
    __shared__ float tile[32][33];
    int s0 = blockIdx.x * 32, d0 = blockIdx.y * 32;
    int bk = blockIdx.z;
    int b = bk >> 2, kvh = bk & 3;
    int t = threadIdx.x;
    int r = t >> 3, c4 = (t & 7) * 4;
    float4 v = *(const float4*)(vb + (((size_t)(b * S_ + s0 + r)) * KV_ + kvh) * HD_ + d0 + c4);
    tile[r][c4] = v.x; tile[r][c4+1] = v.y; tile[r][c4+2] = v.z; tile[r][c4+3] = v.w;
    __syncthreads();
    int dr = t >> 3, s4 = (t & 7) * 4;
    ushort4 o;
    o.x = f2bf(tile[s4][dr]);   o.y = f2bf(tile[s4+1][dr]);
    o.z = f2bf(tile[s4+2][dr]); o.w = f2bf(tile[s4+3][dr]);
    *(ushort4*)(Vt + (((size_t)(b * KV_ + kvh)) * HD_ + d0 + dr) * S_ + s0 + s4) = o;
}

// ------------------------------------------------------------------
// flash attention: block = (q-tile 64, head, batch), 4 waves x 16 q-rows.
__global__ __launch_bounds__(256) void flash_attn(const u16* __restrict__ Qc,
                                                  const u16* __restrict__ Kc,
                                                  const u16* __restrict__ Vt,
                                                  const int* __restrict__ am,
                                                  u16* __restrict__ o) {
    __shared__ __align__(16) u16 Ks[64 * 128];     // [k-row][d], swizzled 16B chunks
    __shared__ __align__(16) u16 Vs[128 * 64];     // [d-row][k], swizzled
    __shared__ __align__(16) u16 Ps[4][16][72];    // per-wave P, padded rows (144B)
    __shared__ int am_s[KBLK];
    int qt = blockIdx.x, h = blockIdx.y, b = blockIdx.z;
    int kvh = h >> 2;
    int tid = threadIdx.x, lane = tid & 63, w = tid >> 6;
    int g = lane >> 4, li = lane & 15;

    // Q fragments (held in regs for the whole block)
    bf16x8 qf[4];
    const u16* qb = Qc + (((size_t)(b * H_ + h)) * S_ + qt * QBLK + w * 16 + li) * HD_;
    #pragma unroll
    for (int dd = 0; dd < 4; dd++) qf[dd] = *(const bf16x8*)(qb + dd * 32 + g * 8);

    float m_r[4], l_r[4];
    f32x4 oacc[8];
    #pragma unroll
    for (int r = 0; r < 4; r++) { m_r[r] = -1e30f; l_r[r] = 0.f; }
    #pragma unroll
    for (int d = 0; d < 8; d++) oacc[d] = (f32x4){0.f, 0.f, 0.f, 0.f};

    const u16* Kg = Kc + ((size_t)(b * KV_ + kvh)) * S_ * HD_;
    const u16* Vg = Vt + ((size_t)(b * KV_ + kvh)) * HD_ * S_;
    int qg0 = qt * QBLK + w * 16 + g * 4;

    for (int kvt = 0; kvt <= qt; kvt++) {
        int kv0 = kvt * KBLK;
        // ---- stage K tile (64 rows x 256B = 16 chunks/row) ----
        #pragma unroll
        for (int qq = 0; qq < 4; qq++) {
            int u = qq * 256 + tid;
            int row = u >> 4, p = u & 15;
            gload16(Kg + (size_t)(kv0 + row) * HD_ + (p ^ (row & 7)) * 8, (char*)Ks + u * 16);
        }
        // ---- stage V^T tile (128 rows x 128B = 8 chunks/row) ----
        #pragma unroll
        for (int qq = 0; qq < 4; qq++) {
            int u = qq * 256 + tid;
            int row = u >> 3, p = u & 7;
            gload16(Vg + (size_t)row * S_ + kv0 + (p ^ (row & 7)) * 8, (char*)Vs + u * 16);
        }
        if (tid < KBLK) am_s[tid] = am[b * S_ + kv0 + tid];
        __syncthreads();

        // ---- QK^T: S[16q][64k] per wave ----
        float ps[4][4];
        #pragma unroll
        for (int kt = 0; kt < 4; kt++) {
            f32x4 sa = (f32x4){0.f, 0.f, 0.f, 0.f};
            int row = kt * 16 + li;
            #pragma unroll
            for (int dd = 0; dd < 4; dd++) {
                int c = dd * 4 + g;
                bf16x8 kf = *(const bf16x8*)((const char*)Ks + ((row * 16 + (c ^ (row & 7))) << 4));
                sa = __builtin_amdgcn_mfma_f32_16x16x32_bf16(qf[dd], kf, sa, 0, 0, 0);
            }
            int kcol = kv0 + kt * 16 + li;
            int amok = am_s[kt * 16 + li];
            #pragma unroll
            for (int r = 0; r < 4; r++) {
                float s = sa[r] * 0.08838834764831845f;
                ps[kt][r] = (amok && kcol <= qg0 + r) ? s : -1e9f;
            }
        }

        // ---- online softmax (row stats across 16-lane col groups) ----
        float rmax[4], rsum[4], scl[4];
        #pragma unroll
        for (int r = 0; r < 4; r++)
            rmax[r] = fmaxf(fmaxf(ps[0][r], ps[1][r]), fmaxf(ps[2][r], ps[3][r]));
        #pragma unroll
        for (int msk = 1; msk < 16; msk <<= 1)
            #pragma unroll
            for (int r = 0; r < 4; r++) rmax[r] = fmaxf(rmax[r], __shfl_xor(rmax[r], msk));
        #pragma unroll
        for (int r = 0; r < 4; r++) {
            float mn = fmaxf(m_r[r], rmax[r]);
            scl[r] = __expf(m_r[r] - mn);
            m_r[r] = mn;
            rsum[r] = 0.f;
        }
        #pragma unroll
        for (int kt = 0; kt < 4; kt++)
            #pragma unroll
            for (int r = 0; r < 4; r++) {
                float p = __expf(ps[kt][r] - m_r[r]);
                ps[kt][r] = p;
                rsum[r] += p;
            }
        #pragma unroll
        for (int msk = 1; msk < 16; msk <<= 1)
            #pragma unroll
            for (int r = 0; r < 4; r++) rsum[r] += __shfl_xor(rsum[r], msk);
        #pragma unroll
        for (int r = 0; r < 4; r++) l_r[r] = l_r[r] * scl[r] + rsum[r];
        #pragma unroll
        for (int d = 0; d < 8; d++)
            #pragma unroll
            for (int r = 0; r < 4; r++) oacc[d][r] *= scl[r];

        // ---- P -> bf16 LDS (per-wave tile, padded) ----
        #pragma unroll
        for (int kt = 0; kt < 4; kt++)
            #pragma unroll
            for (int r = 0; r < 4; r++)
                Ps[w][g * 4 + r][kt * 16 + li] = f2bf(ps[kt][r]);
        __syncthreads();

        // ---- PV: O[16q][128d] += P @ V ----
        bf16x8 pf[2];
        #pragma unroll
        for (int ks = 0; ks < 2; ks++)
            pf[ks] = *(const bf16x8*)&Ps[w][li][ks * 32 + g * 8];
        #pragma unroll
        for (int dblk = 0; dblk < 8; dblk++) {
            int row = dblk * 16 + li;
            #pragma unroll
            for (int ks = 0; ks < 2; ks++) {
                int c = ks * 4 + g;
                bf16x8 vf = *(const bf16x8*)((const char*)Vs + ((row * 8 + (c ^ (row & 7))) << 4));
                oacc[dblk] = __builtin_amdgcn_mfma_f32_16x16x32_bf16(pf[ks], vf, oacc[dblk], 0, 0, 0);
            }
        }
        __syncthreads();
    }

    // ---- epilogue: O /= l, write bf16 [BS][H][128] ----
    float invl[4];
    #pragma unroll
    for (int r = 0; r < 4; r++) invl[r] = 1.f / l_r[r];
    #pragma unroll
    for (int dblk = 0; dblk < 8; dblk++)
        #pragma unroll
        for (int r = 0; r < 4; r++) {
            int qrow = qg0 + r;
            o[(((size_t)b * S_ + qrow) * H_ + h) * HD_ + dblk * 16 + li] =
                f2bf(oacc[dblk][r] * invl[r]);
        }
}

// ------------------------------------------------------------------
__global__ __launch_bounds__(256) void pool_kernel(const float* __restrict__ h,
                                                   const int* __restrict__ am,
                                                   float* __restrict__ out) {
    int b = blockIdx.y;
    int d = blockIdx.x * 256 + threadIdx.x;
    float acc = 0.f, ms = 0.f;
    for (int s = 0; s < S_; s++) {
        float mm = (float)am[b * S_ + s];
        ms  += mm;
        acc += mm * h[((size_t)b * S_ + s) * D_ + d];
    }
    out[(size_t)b * D_ + d] = acc / fmaxf(ms, 1e-9f);
}

// ------------------------------------------------------------------
extern "C" void kernel_launch(void* const* d_in, const int* in_sizes, int n_in,
                              void* d_out, int out_size, void* d_ws, size_t ws_size,
                              hipStream_t stream) {
    const float* embed = (const float*)d_in[0];
    const float* wq    = (const float*)d_in[1];
    const float* wk    = (const float*)d_in[2];
    const float* wv    = (const float*)d_in[3];
    const float* wo    = (const float*)d_in[4];
    const float* laq   = (const float*)d_in[5];
    const float* lbq   = (const float*)d_in[6];
    const float* lav   = (const float*)d_in[7];
    const float* lbv   = (const float*)d_in[8];
    const float* wg    = (const float*)d_in[9];
    const float* wu    = (const float*)d_in[10];
    const float* wd    = (const float*)d_in[11];
    const float* n1    = (const float*)d_in[12];
    const float* n2    = (const float*)d_in[13];
    const float* nf    = (const float*)d_in[14];
    const int*   ids   = (const int*)d_in[15];
    const int*   am    = (const int*)d_in[16];
    float* out = (float*)d_out;

    char* base = (char*)d_ws;
    float* x   = (float*)base;                          // 33.55 MB f32
    u16*   hbf = (u16*)(base + 33554432);               // 16.78 MB bf16
    u16*   obf = (u16*)(base + 50331648);               // 16.78 MB bf16
    char*  Rg  = base + 67108864;                       // 67.11 MB multi-purpose
    float* q   = (float*)Rg;                            // 33.55 MB f32
    float* kb  = (float*)(Rg + 33554432);               // 8.39 MB f32
    float* vb  = (float*)(Rg + 41943040);               // 8.39 MB f32
    u16*   act = (u16*)Rg;                              // 67.11 MB bf16 (after attn)
    float* hf  = (float*)Rg;                            // final norm f32 (after MLP)
    float* t16 = (float*)(base + 134217728);            // 0.26 MB
    u16*   wT0 = (u16*)(base + 134479872);              // 33.55 MB bf16
    u16*   wT1 = (u16*)(base + 168034304);              // 33.55 MB bf16
    u16*   Qc  = (u16*)(base + 201588736);              // 16.78 MB bf16
    u16*   Kc  = (u16*)(base + 218365952);              // 4.19 MB bf16
    u16*   Vtb = (u16*)(base + 222560256);              // 4.19 MB bf16
    // total ~226.8 MB

    embed_kernel<<<BS_, 256, 0, stream>>>(embed, ids, x);

    for (int l = 0; l < NL_; l++) {
        const float* wql = wq + (size_t)l * D_ * D_;
        const float* wkl = wk + (size_t)l * D_ * (KV_*HD_);
        const float* wvl = wv + (size_t)l * D_ * (KV_*HD_);
        const float* wol = wo + (size_t)l * D_ * D_;
        const float* wgl = wg + (size_t)l * D_ * F_;
        const float* wul = wu + (size_t)l * D_ * F_;
        const float* wdl = wd + (size_t)l * F_ * D_;

        rmsnorm_kernel<1><<<BS_, 256, 0, stream>>>(x, n1 + (size_t)l * D_, hbf);

        // q projection
        convt_kernel<<<dim3(D_/32, D_/32), 256, 0, stream>>>(wql, wT0, D_, D_);
        gemm_bt<0><<<dim3(D_/128, BS_/128), 256, 0, stream>>>(hbf, wT0, q, D_, D_);
        lora_a_kernel<<<BS_/16, 256, 0, stream>>>(hbf, laq + (size_t)l * R_ * D_, t16);
        lora_b_kernel<<<BS_, 256, 0, stream>>>(t16, lbq + (size_t)l * D_ * R_, q, D_);

        // k, v projections
        convt_kernel<<<dim3((KV_*HD_)/32, D_/32), 256, 0, stream>>>(wkl, wT0, D_, KV_*HD_);
        gemm_bt<0><<<dim3((KV_*HD_)/128, BS_/128), 256, 0, stream>>>(hbf, wT0, kb, KV_*HD_, D_);
        convt_kernel<<<dim3((KV_*HD_)/32, D_/32), 256, 0, stream>>>(wvl, wT0, D_, KV_*HD_);
        gemm_bt<0><<<dim3((KV_*HD_)/128, BS_/128), 256, 0, stream>>>(hbf, wT0, vb, KV_*HD_, D_);
        lora_a_kernel<<<BS_/16, 256, 0, stream>>>(hbf, lav + (size_t)l * R_ * D_, t16);
        lora_b_kernel<<<BS_, 256, 0, stream>>>(t16, lbv + (size_t)l * (KV_*HD_) * R_, vb, KV_*HD_);

        // RoPE + layout conversion for attention
        qconv_rope<<<dim3(BS_, H_),  64, 0, stream>>>(q,  Qc);
        kconv_rope<<<dim3(BS_, KV_), 64, 0, stream>>>(kb, Kc);
        vconv_t<<<dim3(S_/32, HD_/32, B_*KV_), 256, 0, stream>>>(vb, Vtb);

        flash_attn<<<dim3(S_/QBLK, H_, B_), 256, 0, stream>>>(Qc, Kc, Vtb, am, obf);

        // o projection (accumulate into residual x)
        convt_kernel<<<dim3(D_/32, D_/32), 256, 0, stream>>>(wol, wT0, D_, D_);
        gemm_bt<1><<<dim3(D_/128, BS_/128), 256, 0, stream>>>(obf, wT0, x, D_, D_);

        // MLP
        rmsnorm_kernel<1><<<BS_, 256, 0, stream>>>(x, n2 + (size_t)l * D_, hbf);
        convt_kernel<<<dim3(F_/32, D_/32), 256, 0, stream>>>(wgl, wT0, D_, F_);
        convt_kernel<<<dim3(F_/32, D_/32), 256, 0, stream>>>(wul, wT1, D_, F_);
        gemm_gateup_bt<<<dim3(F_/64, BS_/128), 256, 0, stream>>>(hbf, wT0, wT1, act, F_, D_);
        convt_kernel<<<dim3(D_/32, F_/32), 256, 0, stream>>>(wdl, wT0, F_, D_);
        gemm_bt<1><<<dim3(D_/128, BS_/128), 256, 0, stream>>>(act, wT0, x, D_, F_);
    }

    rmsnorm_kernel<0><<<BS_, 256, 0, stream>>>(x, nf, hf);
    pool_kernel<<<dim3(D_/256, B_), 256, 0, stream>>>(hf, am, out);
}